// Round 9
// baseline (176.897 us; speedup 1.0000x reference)
//
#include <hip/hip_runtime.h>
#include <math.h>

#define BB 64
#define MM 128
#define DDIM 2048
#define KK 32
#define NFR (BB*MM)              // 8192
#define OUTROW (DDIM + KK*DDIM)  // 67584

typedef __attribute__((ext_vector_type(8))) short bf16x8;
typedef __attribute__((ext_vector_type(4))) float f32x4;

// float -> bf16 RNE (inputs finite; no NaN handling needed)
__device__ __forceinline__ short f2bf(float f) {
  unsigned u = __builtin_bit_cast(unsigned, f);
  u += 0x7fffu + ((u >> 16) & 1u);
  return (short)(u >> 16);
}
__device__ __forceinline__ bf16x8 cvt8(float4 a, float4 b) {
  return (bf16x8){f2bf(a.x), f2bf(a.y), f2bf(a.z), f2bf(a.w),
                  f2bf(b.x), f2bf(b.y), f2bf(b.z), f2bf(b.w)};
}
__device__ __forceinline__ unsigned pack2(float lo, float hi) {
  return (unsigned)(unsigned short)f2bf(lo) | ((unsigned)(unsigned short)f2bf(hi) << 16);
}

// ---------------------------------------------------------------------------
// K1: fused W-cvt + logits GEMM (bf16 MFMA) + ssq + softmax + mask.
// 512 threads / 8 waves per block; wave owns a 256-d slice -> 16 waves/CU
// (2 blocks/CU) for 2x the latency hiding of the r8 version. W is read as
// fp32 straight from the input (L2-hot, 256 KB) and converted inline,
// eliminating the k_prep dispatch. Grid 512 x 512; block = 16 frames.
// ---------------------------------------------------------------------------
__global__ __launch_bounds__(512, 4) void k_logits(const float* __restrict__ x,
    const int* __restrict__ lengths, const float* __restrict__ W,
    short* __restrict__ aT, float* __restrict__ asum_p) {
  const int t = threadIdx.x, wv = t >> 6, lane = t & 63;
  const int l15 = lane & 15, quad = lane >> 4;
  const int fg = blockIdx.x;           // 0..511
  const int g0 = fg * 16;              // first frame of block
  const int b  = fg >> 3;              // 8 blocks per batch
  const int m0 = (fg & 7) * 16;        // frame offset within batch
  const int len = lengths[b];
  const bool av = (m0 + l15) < len;    // lane's frame valid

  const float* xrow = x + (size_t)(g0 + l15) * DDIM + wv * 256 + quad * 8;
  const float* w0   = W + (size_t)l15 * DDIM + wv * 256 + quad * 8;
  const float* w1   = w0 + 16 * DDIM;

  f32x4 c0 = {0.f, 0.f, 0.f, 0.f}, c1 = {0.f, 0.f, 0.f, 0.f};
  float ssq = 0.f;
  #pragma unroll
  for (int s = 0; s < 8; ++s) {
    float4 xa = make_float4(0.f, 0.f, 0.f, 0.f);
    float4 xc = make_float4(0.f, 0.f, 0.f, 0.f);
    if (av) {
      xa = *(const float4*)(xrow + s * 32);
      xc = *(const float4*)(xrow + s * 32 + 4);
    }
    float4 wa0 = *(const float4*)(w0 + s * 32);
    float4 wb0 = *(const float4*)(w0 + s * 32 + 4);
    float4 wa1 = *(const float4*)(w1 + s * 32);
    float4 wb1 = *(const float4*)(w1 + s * 32 + 4);
    ssq = fmaf(xa.x, xa.x, ssq); ssq = fmaf(xa.y, xa.y, ssq);
    ssq = fmaf(xa.z, xa.z, ssq); ssq = fmaf(xa.w, xa.w, ssq);
    ssq = fmaf(xc.x, xc.x, ssq); ssq = fmaf(xc.y, xc.y, ssq);
    ssq = fmaf(xc.z, xc.z, ssq); ssq = fmaf(xc.w, xc.w, ssq);
    bf16x8 A  = cvt8(xa, xc);
    bf16x8 B0 = cvt8(wa0, wb0);
    bf16x8 B1 = cvt8(wa1, wb1);
    c0 = __builtin_amdgcn_mfma_f32_16x16x32_bf16(A, B0, c0, 0, 0, 0);
    c1 = __builtin_amdgcn_mfma_f32_16x16x32_bf16(A, B1, c1, 0, 0, 0);
  }

  // ssq partial: frame g0+l15, this wave's 256-d slice
  ssq += __shfl_xor(ssq, 16, 64);
  ssq += __shfl_xor(ssq, 32, 64);
  __shared__ float sq[8][16];
  __shared__ float lg[8][16][33];
  if (quad == 0) sq[wv][l15] = ssq;
  // C layout: row(frame) = quad*4+reg, col(k) = l15
  #pragma unroll
  for (int r = 0; r < 4; ++r) {
    lg[wv][quad * 4 + r][l15]      = c0[r];
    lg[wv][quad * 4 + r][16 + l15] = c1[r];
  }
  __syncthreads();

  // softmax phase: 32 threads per frame, 1 cluster each
  const int fr = t >> 5, kk = t & 31;
  float s0 = 0.f;
  #pragma unroll
  for (int w = 0; w < 8; ++w) s0 += lg[w][fr][kk];
  float ss = 0.f;
  #pragma unroll
  for (int w = 0; w < 8; ++w) ss += sq[w][fr];
  float inv = 1.f / fmaxf(sqrtf(ss), 1e-12f);
  s0 *= inv;
  float mx = s0;
  mx = fmaxf(mx, __shfl_xor(mx, 1, 64));
  mx = fmaxf(mx, __shfl_xor(mx, 2, 64));
  mx = fmaxf(mx, __shfl_xor(mx, 4, 64));
  mx = fmaxf(mx, __shfl_xor(mx, 8, 64));
  mx = fmaxf(mx, __shfl_xor(mx, 16, 64));
  float e0 = __expf(s0 - mx);
  float se = e0;
  se += __shfl_xor(se, 1, 64);
  se += __shfl_xor(se, 2, 64);
  se += __shfl_xor(se, 4, 64);
  se += __shfl_xor(se, 8, 64);
  se += __shfl_xor(se, 16, 64);
  const bool valid = (m0 + fr) < len;
  float a0 = valid ? (e0 / se) : 0.f;

  __syncthreads();                    // done reading lg; reuse for asum
  lg[0][fr][kk] = a0;
  __syncthreads();
  if (t < KK) {
    float s = 0.f;
    #pragma unroll
    for (int f = 0; f < 16; ++f) s += lg[0][f][t];
    asum_p[(size_t)fg * KK + t] = s;
  }
  // a' = a * invn, transposed store [b][k][m]
  aT[(size_t)b * KK * MM + (size_t)kk * MM + m0 + fr] = f2bf(a0 * inv);
}

// ---------------------------------------------------------------------------
// K2: vlad GEMM (bf16 MFMA), K-split for occupancy: grid (8 dc, 64 b, 2 ks)
// = 1024 blocks at 4 blocks/CU -> 16 waves/CU. Each block computes 16
// clusters x 256 d. x loads masked zero-fill, batched per 32-m chunk;
// XOR-swizzled wave-private LDS transpose (reads 2-way = free).
// ---------------------------------------------------------------------------
__global__ __launch_bounds__(256, 4) void k_vlad(const float* __restrict__ x,
    const int* __restrict__ lengths, const float* __restrict__ Cc,
    const short* __restrict__ aT, const float* __restrict__ asum_p,
    float* __restrict__ out, float* __restrict__ ssq_part) {
  const int t = threadIdx.x, wv = t >> 6, lane = t & 63;
  const int l15 = lane & 15, quad = lane >> 4;
  const int dc = blockIdx.x, b = blockIdx.y, ks = blockIdx.z;
  const int k0 = ks * 16;
  const int dw0 = dc * 256 + wv * 64;   // wave d-base
  const int len = lengths[b];

  __shared__ short xbt[4][64][40];      // [wave][d-local][swizzled m], 80B rows
  __shared__ float asl[16];
  __shared__ float ssw[4][16];

  if (t < 16) {
    float s = 0.f;
    #pragma unroll
    for (int p = 0; p < 8; ++p) s += asum_p[(size_t)(b * 8 + p) * KK + k0 + t];
    asl[t] = s;
  }

  const float* xb  = x  + (size_t)b * MM * DDIM;
  const short* at0 = aT + (size_t)b * KK * MM + (size_t)(k0 + l15) * MM + quad * 8;

  const int q4   = l15 * 4;             // lane's 4 staged d-rows
  const int mrow = quad * 2;            // even m within pass group
  const int keyw = l15 & 3;             // store swizzle key
  const int keyr = (l15 >> 2) & 3;      // read swizzle key

  // preload A-frags for this k-half (L2-hot)
  bf16x8 A[4];
  #pragma unroll
  for (int ms = 0; ms < 4; ++ms) A[ms] = *(const bf16x8*)(at0 + ms * 32);

  f32x4 acc[4];
  #pragma unroll
  for (int nt = 0; nt < 4; ++nt) acc[nt] = (f32x4){0.f, 0.f, 0.f, 0.f};
  float avg[4] = {0.f, 0.f, 0.f, 0.f};

  #pragma unroll
  for (int ms = 0; ms < 4; ++ms) {
    // batch 8 masked x loads (independent, in flight together)
    float4 v0[4], v1[4];
    #pragma unroll
    for (int p = 0; p < 4; ++p) {
      const int m = ms * 32 + p * 8 + mrow;
      const float* xr = xb + (size_t)m * DDIM + dw0 + q4;
      v0[p] = (m < len) ? *(const float4*)xr : make_float4(0.f, 0.f, 0.f, 0.f);
      v1[p] = (m + 1 < len) ? *(const float4*)(xr + DDIM)
                            : make_float4(0.f, 0.f, 0.f, 0.f);
    }
    #pragma unroll
    for (int p = 0; p < 4; ++p) {
      avg[0] += v0[p].x + v1[p].x;
      avg[1] += v0[p].y + v1[p].y;
      avg[2] += v0[p].z + v1[p].z;
      avg[3] += v0[p].w + v1[p].w;
      const int mls = (p ^ keyw) * 8 + mrow;  // swizzled m-slot
      *(unsigned*)&xbt[wv][q4 + 0][mls] = pack2(v0[p].x, v1[p].x);
      *(unsigned*)&xbt[wv][q4 + 1][mls] = pack2(v0[p].y, v1[p].y);
      *(unsigned*)&xbt[wv][q4 + 2][mls] = pack2(v0[p].z, v1[p].z);
      *(unsigned*)&xbt[wv][q4 + 3][mls] = pack2(v0[p].w, v1[p].w);
    }
    // wave-private tile: same-wave DS ordering is program order
    #pragma unroll
    for (int nt = 0; nt < 4; ++nt) {
      bf16x8 B = *(const bf16x8*)&xbt[wv][nt * 16 + l15][(quad ^ keyr) * 8];
      acc[nt] = __builtin_amdgcn_mfma_f32_16x16x32_bf16(A[ms], B, acc[nt], 0, 0, 0);
    }
  }

  if (ks == 0) {
    #pragma unroll
    for (int c = 0; c < 4; ++c) {
      avg[c] += __shfl_xor(avg[c], 16, 64);
      avg[c] += __shfl_xor(avg[c], 32, 64);
    }
    if (quad == 0) {
      float rl = 1.f / (float)len;
      *(float4*)(out + (size_t)b * OUTROW + dw0 + q4) =
          make_float4(avg[0] * rl, avg[1] * rl, avg[2] * rl, avg[3] * rl);
    }
  }

  __syncthreads();   // asl ready
  float* orow = out + (size_t)b * OUTROW + DDIM;
  #pragma unroll
  for (int r = 0; r < 4; ++r) {
    const int kl = quad * 4 + r;        // k-local 0..15
    const int k  = k0 + kl;
    const float as = asl[kl];
    float sqv = 0.f;
    #pragma unroll
    for (int nt = 0; nt < 4; ++nt) {
      const int d = dw0 + nt * 16 + l15;
      float v = acc[nt][r] - as * Cc[(size_t)k * DDIM + d];
      orow[(size_t)k * DDIM + d] = v;
      sqv = fmaf(v, v, sqv);
    }
    sqv += __shfl_xor(sqv, 1, 64);
    sqv += __shfl_xor(sqv, 2, 64);
    sqv += __shfl_xor(sqv, 4, 64);
    sqv += __shfl_xor(sqv, 8, 64);
    if (l15 == 0) ssw[wv][kl] = sqv;
  }
  __syncthreads();
  if (t < 16)
    ssq_part[((size_t)dc * BB + b) * KK + k0 + t] =
        ssw[0][t] + ssw[1][t] + ssw[2][t] + ssw[3][t];
}

// ---------------------------------------------------------------------------
// K3: fused scales + apply. grid (32 k, 64 b) x 256.
// ---------------------------------------------------------------------------
__global__ __launch_bounds__(256) void k_norm(const float* __restrict__ ssq_part,
    float* __restrict__ out) {
  const int t = threadIdx.x;
  const int k = blockIdx.x;
  const int b = blockIdx.y;
  __shared__ float ssk[32];
  if (t < 32) {
    float sk = 0.f;
    #pragma unroll
    for (int dc = 0; dc < 8; ++dc)
      sk += ssq_part[((size_t)dc * BB + b) * KK + t];
    ssk[t] = sk;
  }
  __syncthreads();
  float gss = 0.f, iv_own = 0.f;
  #pragma unroll
  for (int kk = 0; kk < 32; ++kk) {
    float nk = sqrtf(ssk[kk]);
    float iv = 1.f / fmaxf(nk, 1e-12f);
    float nn = nk * iv;
    gss += nn * nn;
    if (kk == k) iv_own = iv;
  }
  float sc = iv_own / fmaxf(sqrtf(gss), 1e-12f);
  float* row = out + (size_t)b * OUTROW + DDIM + (size_t)k * DDIM;
  #pragma unroll
  for (int h = 0; h < 2; ++h) {
    float4* p = (float4*)(row + h * 1024 + t * 4);
    float4 v = *p;
    v.x *= sc; v.y *= sc; v.z *= sc; v.w *= sc;
    *p = v;
  }
}

// ---------------------------------------------------------------------------
extern "C" void kernel_launch(void* const* d_in, const int* in_sizes, int n_in,
                              void* d_out, int out_size, void* d_ws, size_t ws_size,
                              hipStream_t stream) {
  const float* x       = (const float*)d_in[0];
  const int*   lengths = (const int*)d_in[1];
  const float* W       = (const float*)d_in[2];
  const float* C       = (const float*)d_in[3];
  float* out = (float*)d_out;

  short* aT     = (short*)d_ws;                          // 64*32*128 shorts
  float* asum_p = (float*)(aT + (size_t)BB * KK * MM);   // 512*32
  float* ssqp   = asum_p + (size_t)512 * KK;             // 8*64*32

  k_logits<<<dim3(512),       512, 0, stream>>>(x, lengths, W, aT, asum_p);
  k_vlad  <<<dim3(8, BB, 2),  256, 0, stream>>>(x, lengths, C, aT, asum_p, out, ssqp);
  k_norm  <<<dim3(KK, BB),    256, 0, stream>>>(ssqp, out);
}

// Round 10
// 148.882 us; speedup vs baseline: 1.1882x; 1.1882x over previous
//
#include <hip/hip_runtime.h>
#include <math.h>

#define BB 64
#define MM 128
#define DDIM 2048
#define KK 32
#define NFR (BB*MM)              // 8192
#define OUTROW (DDIM + KK*DDIM)  // 67584

typedef __attribute__((ext_vector_type(8))) short bf16x8;
typedef __attribute__((ext_vector_type(4))) float f32x4;

// float -> bf16 RNE (inputs finite; no NaN handling needed)
__device__ __forceinline__ short f2bf(float f) {
  unsigned u = __builtin_bit_cast(unsigned, f);
  u += 0x7fffu + ((u >> 16) & 1u);
  return (short)(u >> 16);
}
__device__ __forceinline__ unsigned pack2(float lo, float hi) {
  return (unsigned)(unsigned short)f2bf(lo) | ((unsigned)(unsigned short)f2bf(hi) << 16);
}

// ---------------------------------------------------------------------------
// K0: W fp32 -> bf16 once. 65536 elems, 32 blocks x 256 x 8.
// ---------------------------------------------------------------------------
__global__ __launch_bounds__(256) void k_prep(const float* __restrict__ W,
                                              short* __restrict__ Wb) {
  int i = (blockIdx.x * 256 + threadIdx.x) * 8;
  float4 a = *(const float4*)(W + i);
  float4 b = *(const float4*)(W + i + 4);
  bf16x8 o = {f2bf(a.x), f2bf(a.y), f2bf(a.z), f2bf(a.w),
              f2bf(b.x), f2bf(b.y), f2bf(b.z), f2bf(b.w)};
  *(bf16x8*)(Wb + i) = o;
}

// ---------------------------------------------------------------------------
// K1: fused logits GEMM (bf16 MFMA) + ssq + softmax + mask  (r8 version).
// Per K-half, issue ALL 16 x-loads + 16 W-loads before compute. Invalid
// frames exec-masked zero-fill. Grid 512 x 256; block = 16 frames.
// ---------------------------------------------------------------------------
__global__ __launch_bounds__(256, 2) void k_logits(const float* __restrict__ x,
    const int* __restrict__ lengths, const short* __restrict__ Wb,
    short* __restrict__ aT, float* __restrict__ asum_p) {
  const int t = threadIdx.x, wv = t >> 6, lane = t & 63;
  const int l15 = lane & 15, quad = lane >> 4;
  const int fg = blockIdx.x;           // 0..511
  const int g0 = fg * 16;              // first frame of block
  const int b  = fg >> 3;              // 8 blocks per batch
  const int m0 = (fg & 7) * 16;        // frame offset within batch
  const int len = lengths[b];
  const bool av = (m0 + l15) < len;    // lane's frame valid

  const float* xrow = x + (size_t)(g0 + l15) * DDIM + wv * 512 + quad * 8;
  const short* w0   = Wb + l15 * DDIM + wv * 512 + quad * 8;
  const short* w1   = w0 + 16 * DDIM;

  f32x4 c0 = {0.f, 0.f, 0.f, 0.f}, c1 = {0.f, 0.f, 0.f, 0.f};
  float ssq = 0.f;
  #pragma unroll
  for (int h = 0; h < 2; ++h) {
    float4 xa[8], xc[8];
    bf16x8 B0[8], B1[8];
    #pragma unroll
    for (int s = 0; s < 8; ++s) {
      const int so = h * 8 + s;
      if (av) {
        xa[s] = *(const float4*)(xrow + so * 32);
        xc[s] = *(const float4*)(xrow + so * 32 + 4);
      } else {
        xa[s] = make_float4(0.f, 0.f, 0.f, 0.f);
        xc[s] = make_float4(0.f, 0.f, 0.f, 0.f);
      }
      B0[s] = *(const bf16x8*)(w0 + so * 32);
      B1[s] = *(const bf16x8*)(w1 + so * 32);
    }
    #pragma unroll
    for (int s = 0; s < 8; ++s) {
      ssq = fmaf(xa[s].x, xa[s].x, ssq); ssq = fmaf(xa[s].y, xa[s].y, ssq);
      ssq = fmaf(xa[s].z, xa[s].z, ssq); ssq = fmaf(xa[s].w, xa[s].w, ssq);
      ssq = fmaf(xc[s].x, xc[s].x, ssq); ssq = fmaf(xc[s].y, xc[s].y, ssq);
      ssq = fmaf(xc[s].z, xc[s].z, ssq); ssq = fmaf(xc[s].w, xc[s].w, ssq);
      bf16x8 A = {f2bf(xa[s].x), f2bf(xa[s].y), f2bf(xa[s].z), f2bf(xa[s].w),
                  f2bf(xc[s].x), f2bf(xc[s].y), f2bf(xc[s].z), f2bf(xc[s].w)};
      c0 = __builtin_amdgcn_mfma_f32_16x16x32_bf16(A, B0[s], c0, 0, 0, 0);
      c1 = __builtin_amdgcn_mfma_f32_16x16x32_bf16(A, B1[s], c1, 0, 0, 0);
    }
  }

  ssq += __shfl_xor(ssq, 16, 64);
  ssq += __shfl_xor(ssq, 32, 64);
  __shared__ float sq[4][16];
  __shared__ float lg[4][16][33];
  if (quad == 0) sq[wv][l15] = ssq;
  #pragma unroll
  for (int r = 0; r < 4; ++r) {
    lg[wv][quad * 4 + r][l15]      = c0[r];
    lg[wv][quad * 4 + r][16 + l15] = c1[r];
  }
  __syncthreads();

  const int fr = t >> 4, kk = (t & 15) * 2;
  float s0 = 0.f, s1 = 0.f;
  #pragma unroll
  for (int w = 0; w < 4; ++w) { s0 += lg[w][fr][kk]; s1 += lg[w][fr][kk + 1]; }
  float ss  = sq[0][fr] + sq[1][fr] + sq[2][fr] + sq[3][fr];
  float inv = 1.f / fmaxf(sqrtf(ss), 1e-12f);
  s0 *= inv; s1 *= inv;
  float mx = fmaxf(s0, s1);
  mx = fmaxf(mx, __shfl_xor(mx, 1, 64));
  mx = fmaxf(mx, __shfl_xor(mx, 2, 64));
  mx = fmaxf(mx, __shfl_xor(mx, 4, 64));
  mx = fmaxf(mx, __shfl_xor(mx, 8, 64));
  float e0 = __expf(s0 - mx), e1 = __expf(s1 - mx);
  float se = e0 + e1;
  se += __shfl_xor(se, 1, 64);
  se += __shfl_xor(se, 2, 64);
  se += __shfl_xor(se, 4, 64);
  se += __shfl_xor(se, 8, 64);
  const bool valid = (m0 + fr) < len;
  float rr = valid ? (1.f / se) : 0.f;
  float a0 = e0 * rr, a1 = e1 * rr;

  __syncthreads();
  lg[0][fr][kk] = a0; lg[0][fr][kk + 1] = a1;
  __syncthreads();
  if (t < KK) {
    float s = 0.f;
    #pragma unroll
    for (int f = 0; f < 16; ++f) s += lg[0][f][t];
    asum_p[(size_t)fg * KK + t] = s;
  }
  short* ap = aT + (size_t)b * KK * MM + m0 + fr;
  ap[(size_t)kk * MM]       = f2bf(a0 * inv);
  ap[(size_t)(kk + 1) * MM] = f2bf(a1 * inv);
}

// ---------------------------------------------------------------------------
// K2: vlad GEMM (bf16 MFMA), grid (8 dc, 64 b) x 256, 3 blocks/CU.
// Main loop: masked zero-fill x loads batched per 32-m chunk, XOR-swizzled
// wave-private LDS transpose, MFMA into acc[2][4].
// EPILOGUE FIX (r9 post-mortem): v = acc - asum*C staged into vst[16][268]
// (2-way bank alias = free), then each wave stores one k-row's 256-d slice
// as contiguous 1 KB per instruction -> no HBM write amplification
// (was 6x: scattered dword stores, WRITE_SIZE 108 MB vs 17 MB logical).
// ---------------------------------------------------------------------------
__global__ __launch_bounds__(256, 3) void k_vlad(const float* __restrict__ x,
    const int* __restrict__ lengths, const float* __restrict__ Cc,
    const short* __restrict__ aT, const float* __restrict__ asum_p,
    float* __restrict__ out, float* __restrict__ ssq_part) {
  const int t = threadIdx.x, wv = t >> 6, lane = t & 63;
  const int l15 = lane & 15, quad = lane >> 4;
  const int dc = blockIdx.x, b = blockIdx.y;
  const int dw0 = dc * 256 + wv * 64;   // wave d-base
  const int len = lengths[b];

  __shared__ short xbt[4][64][40];      // [wave][d-local][swizzled m], 80B rows
  __shared__ float vst[16][268];        // staged vlad rows (k-local x 256 d)
  __shared__ float asl[KK];
  __shared__ float ss32[KK];

  if (t < KK) {
    float s = 0.f;
    #pragma unroll
    for (int p = 0; p < 8; ++p) s += asum_p[(size_t)(b * 8 + p) * KK + t];
    asl[t] = s;
  }

  const float* xb  = x  + (size_t)b * MM * DDIM;
  const short* at0 = aT + (size_t)b * KK * MM + (size_t)l15 * MM + quad * 8;

  const int q4   = l15 * 4;             // lane's 4 staged d-rows
  const int mrow = quad * 2;            // even m within pass group
  const int keyw = l15 & 3;             // store swizzle key
  const int keyr = (l15 >> 2) & 3;      // read swizzle key

  // preload A-frags (L2-hot)
  bf16x8 A0[4], A1[4];
  #pragma unroll
  for (int ms = 0; ms < 4; ++ms) {
    A0[ms] = *(const bf16x8*)(at0 + ms * 32);
    A1[ms] = *(const bf16x8*)(at0 + 16 * MM + ms * 32);
  }

  f32x4 acc[2][4];
  #pragma unroll
  for (int kt = 0; kt < 2; ++kt)
    #pragma unroll
    for (int nt = 0; nt < 4; ++nt) acc[kt][nt] = (f32x4){0.f, 0.f, 0.f, 0.f};
  float avg[4] = {0.f, 0.f, 0.f, 0.f};

  #pragma unroll
  for (int ms = 0; ms < 4; ++ms) {
    float4 v0[4], v1[4];
    #pragma unroll
    for (int p = 0; p < 4; ++p) {
      const int m = ms * 32 + p * 8 + mrow;
      const float* xr = xb + (size_t)m * DDIM + dw0 + q4;
      v0[p] = (m < len) ? *(const float4*)xr : make_float4(0.f, 0.f, 0.f, 0.f);
      v1[p] = (m + 1 < len) ? *(const float4*)(xr + DDIM)
                            : make_float4(0.f, 0.f, 0.f, 0.f);
    }
    #pragma unroll
    for (int p = 0; p < 4; ++p) {
      avg[0] += v0[p].x + v1[p].x;
      avg[1] += v0[p].y + v1[p].y;
      avg[2] += v0[p].z + v1[p].z;
      avg[3] += v0[p].w + v1[p].w;
      const int mls = (p ^ keyw) * 8 + mrow;  // swizzled m-slot
      *(unsigned*)&xbt[wv][q4 + 0][mls] = pack2(v0[p].x, v1[p].x);
      *(unsigned*)&xbt[wv][q4 + 1][mls] = pack2(v0[p].y, v1[p].y);
      *(unsigned*)&xbt[wv][q4 + 2][mls] = pack2(v0[p].z, v1[p].z);
      *(unsigned*)&xbt[wv][q4 + 3][mls] = pack2(v0[p].w, v1[p].w);
    }
    // wave-private tile: same-wave DS ordering is program order
    #pragma unroll
    for (int nt = 0; nt < 4; ++nt) {
      bf16x8 B = *(const bf16x8*)&xbt[wv][nt * 16 + l15][(quad ^ keyr) * 8];
      acc[0][nt] = __builtin_amdgcn_mfma_f32_16x16x32_bf16(A0[ms], B, acc[0][nt], 0, 0, 0);
      acc[1][nt] = __builtin_amdgcn_mfma_f32_16x16x32_bf16(A1[ms], B, acc[1][nt], 0, 0, 0);
    }
  }

  // avgpool
  #pragma unroll
  for (int c = 0; c < 4; ++c) {
    avg[c] += __shfl_xor(avg[c], 16, 64);
    avg[c] += __shfl_xor(avg[c], 32, 64);
  }
  if (quad == 0) {
    float rl = 1.f / (float)len;
    *(float4*)(out + (size_t)b * OUTROW + dw0 + q4) =
        make_float4(avg[0] * rl, avg[1] * rl, avg[2] * rl, avg[3] * rl);
  }

  __syncthreads();   // asl ready
  float* orow = out + (size_t)b * OUTROW + DDIM;
  #pragma unroll
  for (int kt = 0; kt < 2; ++kt) {
    // ---- stage v = acc - asum*C into LDS (2-way bank alias, free) ----
    #pragma unroll
    for (int r = 0; r < 4; ++r) {
      const int kl = quad * 4 + r;
      const int k  = kt * 16 + kl;
      const float as = asl[k];
      #pragma unroll
      for (int nt = 0; nt < 4; ++nt) {
        const int d = dw0 + nt * 16 + l15;
        vst[kl][wv * 64 + nt * 16 + l15] =
            acc[kt][nt][r] - as * Cc[(size_t)k * DDIM + d];
      }
    }
    __syncthreads();
    // ---- coalesced store: wave -> one k-row slice (1 KB contiguous) ----
    #pragma unroll
    for (int it = 0; it < 4; ++it) {
      const int kl = it * 4 + wv;
      const int k  = kt * 16 + kl;
      float4 v = *(const float4*)&vst[kl][lane * 4];
      *(float4*)(orow + (size_t)k * DDIM + dc * 256 + lane * 4) = v;
      float sqv = fmaf(v.x, v.x, fmaf(v.y, v.y, fmaf(v.z, v.z, v.w * v.w)));
      sqv += __shfl_xor(sqv, 1, 64);
      sqv += __shfl_xor(sqv, 2, 64);
      sqv += __shfl_xor(sqv, 4, 64);
      sqv += __shfl_xor(sqv, 8, 64);
      sqv += __shfl_xor(sqv, 16, 64);
      sqv += __shfl_xor(sqv, 32, 64);
      if (lane == 0) ss32[k] = sqv;
    }
    __syncthreads();   // before reusing vst (and ss32 writes ordered)
  }
  if (t < KK)
    ssq_part[((size_t)dc * BB + b) * KK + t] = ss32[t];
}

// ---------------------------------------------------------------------------
// K3: fused scales + apply. grid (32 k, 64 b) x 256.
// ---------------------------------------------------------------------------
__global__ __launch_bounds__(256) void k_norm(const float* __restrict__ ssq_part,
    float* __restrict__ out) {
  const int t = threadIdx.x;
  const int k = blockIdx.x;
  const int b = blockIdx.y;
  __shared__ float ssk[32];
  if (t < 32) {
    float sk = 0.f;
    #pragma unroll
    for (int dc = 0; dc < 8; ++dc)
      sk += ssq_part[((size_t)dc * BB + b) * KK + t];
    ssk[t] = sk;
  }
  __syncthreads();
  float gss = 0.f, iv_own = 0.f;
  #pragma unroll
  for (int kk = 0; kk < 32; ++kk) {
    float nk = sqrtf(ssk[kk]);
    float iv = 1.f / fmaxf(nk, 1e-12f);
    float nn = nk * iv;
    gss += nn * nn;
    if (kk == k) iv_own = iv;
  }
  float sc = iv_own / fmaxf(sqrtf(gss), 1e-12f);
  float* row = out + (size_t)b * OUTROW + DDIM + (size_t)k * DDIM;
  #pragma unroll
  for (int h = 0; h < 2; ++h) {
    float4* p = (float4*)(row + h * 1024 + t * 4);
    float4 v = *p;
    v.x *= sc; v.y *= sc; v.z *= sc; v.w *= sc;
    *p = v;
  }
}

// ---------------------------------------------------------------------------
extern "C" void kernel_launch(void* const* d_in, const int* in_sizes, int n_in,
                              void* d_out, int out_size, void* d_ws, size_t ws_size,
                              hipStream_t stream) {
  const float* x       = (const float*)d_in[0];
  const int*   lengths = (const int*)d_in[1];
  const float* W       = (const float*)d_in[2];
  const float* C       = (const float*)d_in[3];
  float* out = (float*)d_out;

  short* Wb     = (short*)d_ws;                          // 32*2048 shorts
  short* aT     = Wb + (size_t)KK * DDIM;                // 64*32*128 shorts
  float* asum_p = (float*)(aT + (size_t)BB * KK * MM);   // 512*32
  float* ssqp   = asum_p + (size_t)512 * KK;             // 8*64*32

  k_prep  <<<dim3(32),     256, 0, stream>>>(W, Wb);
  k_logits<<<dim3(512),    256, 0, stream>>>(x, lengths, Wb, aT, asum_p);
  k_vlad  <<<dim3(8, BB),  256, 0, stream>>>(x, lengths, C, aT, asum_p, out, ssqp);
  k_norm  <<<dim3(KK, BB), 256, 0, stream>>>(ssqp, out);
}